// Round 12
// baseline (474.778 us; speedup 1.0000x reference)
//
#include <hip/hip_runtime.h>
#include <hip/hip_bf16.h>
#include <math.h>

// ---------------------------------------------------------------------------
// GATv2 2-layer + linear head, MI355X (gfx950)
// GEMMs: single-term fp16 MFMA (C = A@W, fp32 accum), 128x128 tile, BK=32,
//   LDS double-buffer (global_load_lds prefetch + explicit waitcnt drain).
// gat_node: half-wave-per-edge fp16 gathers, packed-fp16 logits + fdot2,
//   fp32 softmax/value accum, no-max softmax. Mode 1 fuses the final
//   head linear (h2@Wc+bc) -> writes d_out directly.
// Aux fusion (dispatch count 13 -> 9, single-stream overlap):
//   prep_all     = cvt_f16 + prep_weights + edge_hist   (independent jobs)
//   gemm_scatter = edge_scatter blocks + GEMM-1 blocks  (scatter hides in MFMA)
// CSR build: parallel 3-phase scan.
// ---------------------------------------------------------------------------

#define IN_DIM 256
#define HIDHC 256   // HEADS*HID
#define HID 64
#define OUT_DIM 40

using half8  = __attribute__((ext_vector_type(8))) _Float16;
using half4  = __attribute__((ext_vector_type(4))) _Float16;
using half2v = __attribute__((ext_vector_type(2))) _Float16;
using f32x4  = __attribute__((ext_vector_type(4))) float;

__device__ __forceinline__ void gload16(const void* g, void* l) {
    __builtin_amdgcn_global_load_lds(
        (const __attribute__((address_space(1))) void*)g,
        (__attribute__((address_space(3))) void*)l, 16, 0, 0);
}

// -------------------- fused prep: cvt_f16 | prep_weights | edge_hist --------

__global__ __launch_bounds__(256) void prep_all(
    const float* __restrict__ x, _Float16* __restrict__ Af, int n4,
    const float* __restrict__ W0, const float* __restrict__ W1,
    const float* __restrict__ W2, const float* __restrict__ W3,
    _Float16* __restrict__ T,
    const int* __restrict__ dst, int* __restrict__ deg, int E,
    int nbCvt, int nbW)
{
    int b = blockIdx.x;
    if (b < nbCvt) {
        int i = b * 256 + threadIdx.x;
        if (i < n4) {
            float4 v = ((const float4*)x)[i];
            half4 h = { (_Float16)v.x, (_Float16)v.y, (_Float16)v.z, (_Float16)v.w };
            ((half4*)Af)[i] = h;
        }
        return;
    }
    if (b < nbCvt + nbW) {
        int b2 = b - nbCvt;
        int k = b2 & 255, w = b2 >> 8;
        const float* Wsel = (w == 0) ? W0 : (w == 1) ? W1 : (w == 2) ? W2 : W3;
        int nn = threadIdx.x;
        float v = Wsel[k * 256 + nn];
        T[(size_t)w * 65536 + (size_t)nn * 256 + k] = (_Float16)v;
        return;
    }
    int i = (b - nbCvt - nbW) * 256 + threadIdx.x;
    if (i < E) atomicAdd(&deg[dst[i]], 1);
}

// -------------------- scan phases --------------------

__global__ void deg_block_reduce(const int* __restrict__ deg, int* __restrict__ bsum, int n) {
    int i = blockIdx.x * 256 + threadIdx.x;
    int v = (i < n) ? deg[i] : 0;
    #pragma unroll
    for (int off = 32; off; off >>= 1) v += __shfl_xor(v, off, 64);
    __shared__ int ws[4];
    int lane = threadIdx.x & 63, wid = threadIdx.x >> 6;
    if (lane == 0) ws[wid] = v;
    __syncthreads();
    if (threadIdx.x == 0) bsum[blockIdx.x] = ws[0] + ws[1] + ws[2] + ws[3];
}

__global__ void scan_bsums(const int* __restrict__ bsum, int* __restrict__ bpre, int nb) {
    __shared__ int s[256];
    int tid = threadIdx.x;
    int orig = (tid < nb) ? bsum[tid] : 0;
    s[tid] = orig;
    __syncthreads();
    #pragma unroll
    for (int off = 1; off < 256; off <<= 1) {
        int t = (tid >= off) ? s[tid - off] : 0;
        __syncthreads();
        s[tid] += t;
        __syncthreads();
    }
    if (tid < nb) bpre[tid] = s[tid] - orig;
}

__global__ void deg_scan_apply(const int* __restrict__ deg, const int* __restrict__ bpre,
                               int* __restrict__ offsets, int* __restrict__ cursor, int n) {
    int i = blockIdx.x * 256 + threadIdx.x;
    int lane = threadIdx.x & 63, wid = threadIdx.x >> 6;
    int v = (i < n) ? deg[i] : 0;
    int inc = v;
    #pragma unroll
    for (int off = 1; off < 64; off <<= 1) {
        int t = __shfl_up(inc, off, 64);
        if (lane >= off) inc += t;
    }
    __shared__ int ws[4];
    if (lane == 63) ws[wid] = inc;
    __syncthreads();
    int add = bpre[blockIdx.x];
    for (int w = 0; w < wid; ++w) add += ws[w];
    int incl = inc + add;
    if (i < n) { offsets[i + 1] = incl; cursor[i] = incl - v; }
    if (i == 0) offsets[0] = 0;
}

// -------------------- fused GEMM + edge_scatter --------------------
// blocks [0, scatterBlocks): edge_scatter; rest: dual GEMM (flattened 3D).
// GEMM: C[M,256] = A @ W + bias, fp16 in/out, fp32 accum, 128x128 tile,
// BK=32, LDS ping-pong via global_load_lds with explicit waitcnt drain.

__global__ __launch_bounds__(256) void gemm_scatter(
    const _Float16* __restrict__ A,
    const _Float16* __restrict__ W0, const float* __restrict__ b0, _Float16* __restrict__ C0,
    const _Float16* __restrict__ W1, const float* __restrict__ b1, _Float16* __restrict__ C1,
    int M, int Mb,
    const int* __restrict__ src, const int* __restrict__ dstv,
    int* __restrict__ cursor, int* __restrict__ csr, int E, int scatterBlocks)
{
    __shared__ __align__(16) _Float16 sA[2][4096], sB[2][4096];

    int blk = blockIdx.x;
    if (blk < scatterBlocks) {
        int i = blk * 256 + threadIdx.x;
        if (i < E) {
            int pos = atomicAdd(&cursor[dstv[i]], 1);
            csr[pos] = src[i];
        }
        return;
    }
    int bb = blk - scatterBlocks;
    int bx = bb % Mb;
    int byz = bb / Mb;
    int by = byz & 1, bz = byz >> 1;

    const _Float16* W   = bz ? W1 : W0;
    const float*    bias= bz ? b1 : b0;
    _Float16*       C   = bz ? C1 : C0;

    int tid = threadIdx.x;
    int bm = bx * 128;
    int bn = by * 128;

    int lane = tid & 63, w = tid >> 6;
    int r = lane & 15, q = lane >> 4;
    int m0 = (w >> 1) * 64, n0 = (w & 1) * 64;

    int arow[2], brow[2], kgo[2], lds[2];
    #pragma unroll
    for (int i = 0; i < 2; ++i) {
        int g = tid + 256 * i;
        kgo[i] = (g >> 7) * 8;
        int row = g & 127;
        arow[i] = min(bm + row, M - 1);
        brow[i] = bn + row;
        lds[i] = g * 8;
    }

    f32x4 acc[4][4];
    #pragma unroll
    for (int i = 0; i < 4; ++i)
        #pragma unroll
        for (int j = 0; j < 4; ++j) acc[i][j] = (f32x4)0.f;

    #pragma unroll
    for (int i = 0; i < 2; ++i) {
        gload16(A + (size_t)arow[i] * 256 + kgo[i], &sA[0][lds[i]]);
        gload16(W + (size_t)brow[i] * 256 + kgo[i], &sB[0][lds[i]]);
    }
    __builtin_amdgcn_s_waitcnt(0);
    __syncthreads();

    #pragma unroll 1
    for (int kt = 0; kt < 8; ++kt) {
        int buf = kt & 1;
        if (kt < 7) {
            int k0 = (kt + 1) * 32;
            #pragma unroll
            for (int i = 0; i < 2; ++i) {
                gload16(A + (size_t)arow[i] * 256 + k0 + kgo[i], &sA[buf ^ 1][lds[i]]);
                gload16(W + (size_t)brow[i] * 256 + k0 + kgo[i], &sB[buf ^ 1][lds[i]]);
            }
        }
        half8 a[4], b[4];
        #pragma unroll
        for (int i = 0; i < 4; ++i) {
            a[i] = *(const half8*)(&sA[buf][(q * 128 + m0 + i * 16 + r) * 8]);
            b[i] = *(const half8*)(&sB[buf][(q * 128 + n0 + i * 16 + r) * 8]);
        }
        #pragma unroll
        for (int i = 0; i < 4; ++i)
            #pragma unroll
            for (int j = 0; j < 4; ++j)
                acc[i][j] = __builtin_amdgcn_mfma_f32_16x16x32_f16(a[i], b[j], acc[i][j], 0, 0, 0);
        __builtin_amdgcn_s_waitcnt(0);
        __syncthreads();
    }

    float bv[4];
    #pragma unroll
    for (int j = 0; j < 4; ++j) bv[j] = bias[bn + n0 + j * 16 + r];
    #pragma unroll
    for (int i = 0; i < 4; ++i) {
        #pragma unroll
        for (int reg = 0; reg < 4; ++reg) {
            int row = bm + m0 + i * 16 + q * 4 + reg;
            if (row < M) {
                #pragma unroll
                for (int j = 0; j < 4; ++j)
                    C[(size_t)row * 256 + bn + n0 + j * 16 + r] =
                        (_Float16)(acc[i][j][reg] + bv[j]);
            }
        }
    }
}

// -------------------- GAT node kernel: half-wave-per-edge --------------------
// mode 0: h1 = relu(agg + bias1) fp16 [N,256] -> out0
// mode 1: h2 = relu(mean_heads + bias2); out0 = h2 @ Wc + bc  (fused head)

__global__ __launch_bounds__(256) void gat_node(
    const _Float16* __restrict__ xl, const _Float16* __restrict__ xr,
    const float* __restrict__ att, const float* __restrict__ bias,
    const int* __restrict__ offsets, const int* __restrict__ csr_src,
    void* __restrict__ out0, const float* __restrict__ Wc,
    const float* __restrict__ bc, int n, int mode)
{
    __shared__ float sWc[HID * OUT_DIM];
    __shared__ float sbc[OUT_DIM];
    if (mode == 1) {
        for (int i = threadIdx.x; i < HID * OUT_DIM; i += 256) sWc[i] = Wc[i];
        if (threadIdx.x < OUT_DIM) sbc[threadIdx.x] = bc[threadIdx.x];
        __syncthreads();
    }

    int wid = threadIdx.x >> 6;
    int node = (blockIdx.x << 2) + wid;
    if (node >= n) return;
    int lane = threadIdx.x & 63;
    int H = lane >> 5;
    int p = lane & 31;

    const half2v c02 = { (_Float16)0.2f, (_Float16)0.2f };

    half8 xrh = *(const half8*)(xr + (size_t)node * HIDHC + p * 8);
    half2v xr01 = __builtin_shufflevector(xrh, xrh, 0, 1);
    half2v xr23 = __builtin_shufflevector(xrh, xrh, 2, 3);
    half2v xr45 = __builtin_shufflevector(xrh, xrh, 4, 5);
    half2v xr67 = __builtin_shufflevector(xrh, xrh, 6, 7);

    float4 af0 = *(const float4*)(att + p * 8);
    float4 af1 = *(const float4*)(att + p * 8 + 4);
    half2v at01 = { (_Float16)af0.x, (_Float16)af0.y };
    half2v at23 = { (_Float16)af0.z, (_Float16)af0.w };
    half2v at45 = { (_Float16)af1.x, (_Float16)af1.y };
    half2v at67 = { (_Float16)af1.z, (_Float16)af1.w };

    float acc[8];
    #pragma unroll
    for (int k = 0; k < 8; ++k) acc[k] = 0.f;
    float d = 0.f;

    int j0 = __builtin_amdgcn_readfirstlane(offsets[node]);
    int j1 = __builtin_amdgcn_readfirstlane(offsets[node + 1]);

    int j = j0;
    for (; j + 2 <= j1; j += 2) {
        int s0 = __builtin_amdgcn_readfirstlane(csr_src[j]);
        int s1 = __builtin_amdgcn_readfirstlane(csr_src[j + 1]);
        int s = H ? s1 : s0;
        half8 h = *(const half8*)(xl + (size_t)s * HIDHC + p * 8);
        half2v h01 = __builtin_shufflevector(h, h, 0, 1);
        half2v h23 = __builtin_shufflevector(h, h, 2, 3);
        half2v h45 = __builtin_shufflevector(h, h, 4, 5);
        half2v h67 = __builtin_shufflevector(h, h, 6, 7);
        half2v s01 = h01 + xr01, s23 = h23 + xr23, s45 = h45 + xr45, s67 = h67 + xr67;
        half2v l01 = __builtin_elementwise_max(s01, s01 * c02);
        half2v l23 = __builtin_elementwise_max(s23, s23 * c02);
        half2v l45 = __builtin_elementwise_max(s45, s45 * c02);
        half2v l67 = __builtin_elementwise_max(s67, s67 * c02);
        float e = __builtin_amdgcn_fdot2(l01, at01, 0.f, false);
        e = __builtin_amdgcn_fdot2(l23, at23, e, false);
        e = __builtin_amdgcn_fdot2(l45, at45, e, false);
        e = __builtin_amdgcn_fdot2(l67, at67, e, false);
        e += __shfl_xor(e, 1);
        e += __shfl_xor(e, 2);
        e += __shfl_xor(e, 4);
        float pw = __expf(e);
        d += pw;
        #pragma unroll
        for (int k = 0; k < 8; ++k) acc[k] = fmaf(pw, (float)h[k], acc[k]);
    }
    if (j < j1) {
        int s0 = __builtin_amdgcn_readfirstlane(csr_src[j]);
        half8 h = *(const half8*)(xl + (size_t)s0 * HIDHC + p * 8);
        half2v h01 = __builtin_shufflevector(h, h, 0, 1);
        half2v h23 = __builtin_shufflevector(h, h, 2, 3);
        half2v h45 = __builtin_shufflevector(h, h, 4, 5);
        half2v h67 = __builtin_shufflevector(h, h, 6, 7);
        half2v s01 = h01 + xr01, s23 = h23 + xr23, s45 = h45 + xr45, s67 = h67 + xr67;
        half2v l01 = __builtin_elementwise_max(s01, s01 * c02);
        half2v l23 = __builtin_elementwise_max(s23, s23 * c02);
        half2v l45 = __builtin_elementwise_max(s45, s45 * c02);
        half2v l67 = __builtin_elementwise_max(s67, s67 * c02);
        float e = __builtin_amdgcn_fdot2(l01, at01, 0.f, false);
        e = __builtin_amdgcn_fdot2(l23, at23, e, false);
        e = __builtin_amdgcn_fdot2(l45, at45, e, false);
        e = __builtin_amdgcn_fdot2(l67, at67, e, false);
        e += __shfl_xor(e, 1);
        e += __shfl_xor(e, 2);
        e += __shfl_xor(e, 4);
        float pw = (H == 0) ? __expf(e) : 0.f;
        d += pw;
        #pragma unroll
        for (int k = 0; k < 8; ++k) acc[k] = fmaf(pw, (float)h[k], acc[k]);
    }

    d += __shfl_xor(d, 32);
    #pragma unroll
    for (int k = 0; k < 8; ++k) acc[k] += __shfl_xor(acc[k], 32);

    float inv = 1.f / (d + 1e-16f);
    float o[8];
    #pragma unroll
    for (int k = 0; k < 8; ++k) o[k] = acc[k] * inv;

    if (mode == 0) {
        if (H == 0) {
            float4 b0 = *(const float4*)(bias + p * 8);
            float4 b1 = *(const float4*)(bias + p * 8 + 4);
            float bb[8] = { b0.x, b0.y, b0.z, b0.w, b1.x, b1.y, b1.z, b1.w };
            half8 hh;
            #pragma unroll
            for (int k = 0; k < 8; ++k) hh[k] = (_Float16)fmaxf(o[k] + bb[k], 0.f);
            *(half8*)((_Float16*)out0 + (size_t)node * HIDHC + p * 8) = hh;
        }
    } else {
        // head-mean: xor 8 / xor 16 sum over 4 heads -> every lane holds
        // channels (lane&7)*8 + k of the 64-ch h2 row (8-fold replicated)
        #pragma unroll
        for (int k = 0; k < 8; ++k) {
            o[k] += __shfl_xor(o[k], 8);
            o[k] += __shfl_xor(o[k], 16);
        }
        int c = lane & 7;          // channel-block index
        int g = lane >> 3;         // replica group: handles outputs 5g..5g+4
        float4 b0 = *(const float4*)(bias + c * 8);
        float4 b1 = *(const float4*)(bias + c * 8 + 4);
        float bb[8] = { b0.x, b0.y, b0.z, b0.w, b1.x, b1.y, b1.z, b1.w };
        float h2v[8];
        #pragma unroll
        for (int k = 0; k < 8; ++k) h2v[k] = fmaxf(o[k] * 0.25f + bb[k], 0.f);
        // fused head: partial[m] = sum_k h2v[k] * Wc[(c*8+k)][5g+m]
        float partial[5];
        #pragma unroll
        for (int m = 0; m < 5; ++m) {
            float s = 0.f;
            #pragma unroll
            for (int k = 0; k < 8; ++k)
                s = fmaf(h2v[k], sWc[(c * 8 + k) * OUT_DIM + 5 * g + m], s);
            partial[m] = s;
        }
        #pragma unroll
        for (int m = 0; m < 5; ++m) {
            partial[m] += __shfl_xor(partial[m], 1);
            partial[m] += __shfl_xor(partial[m], 2);
            partial[m] += __shfl_xor(partial[m], 4);
        }
        if (c < 5) {
            int oidx = 5 * g + c;
            ((float*)out0)[(size_t)node * OUT_DIM + oidx] = partial[c] + sbc[oidx];
        }
    }
}

// -------------------- launch --------------------

extern "C" void kernel_launch(void* const* d_in, const int* in_sizes, int n_in,
                              void* d_out, int out_size, void* d_ws, size_t ws_size,
                              hipStream_t stream) {
    const int N = in_sizes[0] / IN_DIM;   // 50000
    const int E = in_sizes[1];            // 800000

    const float* x    = (const float*)d_in[0];
    const int*   src  = (const int*)d_in[1];
    const int*   dst  = (const int*)d_in[2];
    const float* Wl1  = (const float*)d_in[3];
    const float* bl1  = (const float*)d_in[4];
    const float* Wr1  = (const float*)d_in[5];
    const float* br1  = (const float*)d_in[6];
    const float* att1 = (const float*)d_in[7];
    const float* bias1= (const float*)d_in[8];
    const float* Wl2  = (const float*)d_in[9];
    const float* bl2  = (const float*)d_in[10];
    const float* Wr2  = (const float*)d_in[11];
    const float* br2  = (const float*)d_in[12];
    const float* att2 = (const float*)d_in[13];
    const float* bias2= (const float*)d_in[14];
    const float* Wc   = (const float*)d_in[15];
    const float* bc   = (const float*)d_in[16];

    char* ws = (char*)d_ws;
    size_t off = 0;
    _Float16* xlh = (_Float16*)(ws + off); off += (size_t)N * HIDHC * 2;  // xl fp16
    _Float16* xrh = (_Float16*)(ws + off); off += (size_t)N * HIDHC * 2;  // xr fp16
    _Float16* Af  = (_Float16*)(ws + off); off += (size_t)N * HIDHC * 2;  // x / h1 fp16
    _Float16* Wt  = (_Float16*)(ws + off); off += (size_t)4 * 65536 * 2;
    int* deg     = (int*)(ws + off); off += (size_t)N * 4;
    int* offsets = (int*)(ws + off); off += (size_t)(N + 1) * 4;
    int* cursor  = (int*)(ws + off); off += (size_t)N * 4;
    int* csr     = (int*)(ws + off); off += (size_t)E * 4;
    int* bsum    = (int*)(ws + off); off += 256 * 4;
    int* bpre    = (int*)(ws + off); off += 256 * 4;

    const int NB = (N + 255) / 256;
    const int n4 = N * HIDHC / 4;
    const int nbCvt = (n4 + 255) / 256;
    const int nbW = 1024;
    const int nbE = (E + 255) / 256;
    const int Mb = (N + 127) / 128;
    const int KW = 65536;

    // 1) zero degree counters
    hipMemsetAsync(deg, 0, (size_t)N * 4, stream);
    // 2) fused prep: x->fp16, W->fp16^T, degree histogram
    prep_all<<<nbCvt + nbW + nbE, 256, 0, stream>>>(x, Af, n4,
        Wl1, Wr1, Wl2, Wr2, Wt, dst, deg, E, nbCvt, nbW);
    // 3-5) parallel scan -> offsets/cursor
    deg_block_reduce<<<NB, 256, 0, stream>>>(deg, bsum, N);
    scan_bsums<<<1, 256, 0, stream>>>(bsum, bpre, NB);
    deg_scan_apply<<<NB, 256, 0, stream>>>(deg, bpre, offsets, cursor, N);
    // 6) layer-1 GEMM + edge_scatter fused (scatter hides under MFMA)
    gemm_scatter<<<nbE + Mb * 4, 256, 0, stream>>>(Af,
        Wt + 0 * KW, bl1, xlh, Wt + 1 * KW, br1, xrh, N, Mb,
        src, dst, cursor, csr, E, nbE);
    // 7) layer-1 attention
    gat_node<<<(N + 3) / 4, 256, 0, stream>>>(xlh, xrh, att1, bias1, offsets, csr,
                                              (void*)Af, Wc, bc, N, 0);
    // 8) layer-2 GEMM (no scatter blocks)
    gemm_scatter<<<Mb * 4, 256, 0, stream>>>(Af,
        Wt + 2 * KW, bl2, xlh, Wt + 3 * KW, br2, xrh, N, Mb,
        src, dst, cursor, csr, E, 0);
    // 9) layer-2 attention + fused head linear -> d_out
    gat_node<<<(N + 3) / 4, 256, 0, stream>>>(xlh, xrh, att2, bias2, offsets, csr,
                                              d_out, Wc, bc, N, 1);
}

// Round 13
// 458.843 us; speedup vs baseline: 1.0347x; 1.0347x over previous
//
#include <hip/hip_runtime.h>
#include <hip/hip_bf16.h>
#include <math.h>

// ---------------------------------------------------------------------------
// GATv2 2-layer + linear head, MI355X (gfx950)
// GEMMs: single-term fp16 MFMA (C = A@W, fp32 accum), 128x128 tile, BK=32,
//   LDS double-buffer (global_load_lds prefetch + explicit waitcnt drain).
// gat_node: half-wave-per-edge fp16 gathers, packed-fp16 logits + fdot2,
//   fp32 softmax/value accum, no-max softmax. Mode 1 fuses the final head
//   (h2@Wc+bc -> d_out); sWc padded stride 41 -> 2-way (free) bank aliasing
//   [round-12 stride-40 layout was 8-way conflicted: 2.8e7 conflict cycles].
// Aux fusion: prep_all = cvt_f16|prep_weights|edge_hist;
//   gemm_scatter = edge_scatter blocks + GEMM blocks (scatter hides in MFMA).
// CSR build: parallel 3-phase scan.
// ---------------------------------------------------------------------------

#define IN_DIM 256
#define HIDHC 256   // HEADS*HID
#define HID 64
#define OUT_DIM 40
#define WCPAD 41    // padded stride for sWc (bank-conflict-free)

using half8  = __attribute__((ext_vector_type(8))) _Float16;
using half4  = __attribute__((ext_vector_type(4))) _Float16;
using half2v = __attribute__((ext_vector_type(2))) _Float16;
using f32x4  = __attribute__((ext_vector_type(4))) float;

__device__ __forceinline__ void gload16(const void* g, void* l) {
    __builtin_amdgcn_global_load_lds(
        (const __attribute__((address_space(1))) void*)g,
        (__attribute__((address_space(3))) void*)l, 16, 0, 0);
}

// -------------------- fused prep: cvt_f16 | prep_weights | edge_hist --------

__global__ __launch_bounds__(256) void prep_all(
    const float* __restrict__ x, _Float16* __restrict__ Af, int n4,
    const float* __restrict__ W0, const float* __restrict__ W1,
    const float* __restrict__ W2, const float* __restrict__ W3,
    _Float16* __restrict__ T,
    const int* __restrict__ dst, int* __restrict__ deg, int E,
    int nbCvt, int nbW)
{
    int b = blockIdx.x;
    if (b < nbCvt) {
        int i = b * 256 + threadIdx.x;
        if (i < n4) {
            float4 v = ((const float4*)x)[i];
            half4 h = { (_Float16)v.x, (_Float16)v.y, (_Float16)v.z, (_Float16)v.w };
            ((half4*)Af)[i] = h;
        }
        return;
    }
    if (b < nbCvt + nbW) {
        int b2 = b - nbCvt;
        int k = b2 & 255, w = b2 >> 8;
        const float* Wsel = (w == 0) ? W0 : (w == 1) ? W1 : (w == 2) ? W2 : W3;
        int nn = threadIdx.x;
        float v = Wsel[k * 256 + nn];
        T[(size_t)w * 65536 + (size_t)nn * 256 + k] = (_Float16)v;
        return;
    }
    int i = (b - nbCvt - nbW) * 256 + threadIdx.x;
    if (i < E) atomicAdd(&deg[dst[i]], 1);
}

// -------------------- scan phases --------------------

__global__ void deg_block_reduce(const int* __restrict__ deg, int* __restrict__ bsum, int n) {
    int i = blockIdx.x * 256 + threadIdx.x;
    int v = (i < n) ? deg[i] : 0;
    #pragma unroll
    for (int off = 32; off; off >>= 1) v += __shfl_xor(v, off, 64);
    __shared__ int ws[4];
    int lane = threadIdx.x & 63, wid = threadIdx.x >> 6;
    if (lane == 0) ws[wid] = v;
    __syncthreads();
    if (threadIdx.x == 0) bsum[blockIdx.x] = ws[0] + ws[1] + ws[2] + ws[3];
}

__global__ void scan_bsums(const int* __restrict__ bsum, int* __restrict__ bpre, int nb) {
    __shared__ int s[256];
    int tid = threadIdx.x;
    int orig = (tid < nb) ? bsum[tid] : 0;
    s[tid] = orig;
    __syncthreads();
    #pragma unroll
    for (int off = 1; off < 256; off <<= 1) {
        int t = (tid >= off) ? s[tid - off] : 0;
        __syncthreads();
        s[tid] += t;
        __syncthreads();
    }
    if (tid < nb) bpre[tid] = s[tid] - orig;
}

__global__ void deg_scan_apply(const int* __restrict__ deg, const int* __restrict__ bpre,
                               int* __restrict__ offsets, int* __restrict__ cursor, int n) {
    int i = blockIdx.x * 256 + threadIdx.x;
    int lane = threadIdx.x & 63, wid = threadIdx.x >> 6;
    int v = (i < n) ? deg[i] : 0;
    int inc = v;
    #pragma unroll
    for (int off = 1; off < 64; off <<= 1) {
        int t = __shfl_up(inc, off, 64);
        if (lane >= off) inc += t;
    }
    __shared__ int ws[4];
    if (lane == 63) ws[wid] = inc;
    __syncthreads();
    int add = bpre[blockIdx.x];
    for (int w = 0; w < wid; ++w) add += ws[w];
    int incl = inc + add;
    if (i < n) { offsets[i + 1] = incl; cursor[i] = incl - v; }
    if (i == 0) offsets[0] = 0;
}

// -------------------- fused GEMM + edge_scatter --------------------

__global__ __launch_bounds__(256) void gemm_scatter(
    const _Float16* __restrict__ A,
    const _Float16* __restrict__ W0, const float* __restrict__ b0, _Float16* __restrict__ C0,
    const _Float16* __restrict__ W1, const float* __restrict__ b1, _Float16* __restrict__ C1,
    int M, int Mb,
    const int* __restrict__ src, const int* __restrict__ dstv,
    int* __restrict__ cursor, int* __restrict__ csr, int E, int scatterBlocks)
{
    __shared__ __align__(16) _Float16 sA[2][4096], sB[2][4096];

    int blk = blockIdx.x;
    if (blk < scatterBlocks) {
        int i = blk * 256 + threadIdx.x;
        if (i < E) {
            int pos = atomicAdd(&cursor[dstv[i]], 1);
            csr[pos] = src[i];
        }
        return;
    }
    int bb = blk - scatterBlocks;
    int bx = bb % Mb;
    int byz = bb / Mb;
    int by = byz & 1, bz = byz >> 1;

    const _Float16* W   = bz ? W1 : W0;
    const float*    bias= bz ? b1 : b0;
    _Float16*       C   = bz ? C1 : C0;

    int tid = threadIdx.x;
    int bm = bx * 128;
    int bn = by * 128;

    int lane = tid & 63, w = tid >> 6;
    int r = lane & 15, q = lane >> 4;
    int m0 = (w >> 1) * 64, n0 = (w & 1) * 64;

    int arow[2], brow[2], kgo[2], lds[2];
    #pragma unroll
    for (int i = 0; i < 2; ++i) {
        int g = tid + 256 * i;
        kgo[i] = (g >> 7) * 8;
        int row = g & 127;
        arow[i] = min(bm + row, M - 1);
        brow[i] = bn + row;
        lds[i] = g * 8;
    }

    f32x4 acc[4][4];
    #pragma unroll
    for (int i = 0; i < 4; ++i)
        #pragma unroll
        for (int j = 0; j < 4; ++j) acc[i][j] = (f32x4)0.f;

    #pragma unroll
    for (int i = 0; i < 2; ++i) {
        gload16(A + (size_t)arow[i] * 256 + kgo[i], &sA[0][lds[i]]);
        gload16(W + (size_t)brow[i] * 256 + kgo[i], &sB[0][lds[i]]);
    }
    __builtin_amdgcn_s_waitcnt(0);
    __syncthreads();

    #pragma unroll 1
    for (int kt = 0; kt < 8; ++kt) {
        int buf = kt & 1;
        if (kt < 7) {
            int k0 = (kt + 1) * 32;
            #pragma unroll
            for (int i = 0; i < 2; ++i) {
                gload16(A + (size_t)arow[i] * 256 + k0 + kgo[i], &sA[buf ^ 1][lds[i]]);
                gload16(W + (size_t)brow[i] * 256 + k0 + kgo[i], &sB[buf ^ 1][lds[i]]);
            }
        }
        half8 a[4], b[4];
        #pragma unroll
        for (int i = 0; i < 4; ++i) {
            a[i] = *(const half8*)(&sA[buf][(q * 128 + m0 + i * 16 + r) * 8]);
            b[i] = *(const half8*)(&sB[buf][(q * 128 + n0 + i * 16 + r) * 8]);
        }
        #pragma unroll
        for (int i = 0; i < 4; ++i)
            #pragma unroll
            for (int j = 0; j < 4; ++j)
                acc[i][j] = __builtin_amdgcn_mfma_f32_16x16x32_f16(a[i], b[j], acc[i][j], 0, 0, 0);
        __builtin_amdgcn_s_waitcnt(0);
        __syncthreads();
    }

    float bv[4];
    #pragma unroll
    for (int j = 0; j < 4; ++j) bv[j] = bias[bn + n0 + j * 16 + r];
    #pragma unroll
    for (int i = 0; i < 4; ++i) {
        #pragma unroll
        for (int reg = 0; reg < 4; ++reg) {
            int row = bm + m0 + i * 16 + q * 4 + reg;
            if (row < M) {
                #pragma unroll
                for (int j = 0; j < 4; ++j)
                    C[(size_t)row * 256 + bn + n0 + j * 16 + r] =
                        (_Float16)(acc[i][j][reg] + bv[j]);
            }
        }
    }
}

// -------------------- GAT node kernel: half-wave-per-edge --------------------
// mode 0: h1 = relu(agg + bias1) fp16 [N,256] -> out0
// mode 1: h2 = relu(mean_heads + bias2); out0 = h2 @ Wc + bc  (fused head,
//         sWc padded stride 41 -> 2-way bank aliasing = free)

__global__ __launch_bounds__(256) void gat_node(
    const _Float16* __restrict__ xl, const _Float16* __restrict__ xr,
    const float* __restrict__ att, const float* __restrict__ bias,
    const int* __restrict__ offsets, const int* __restrict__ csr_src,
    void* __restrict__ out0, const float* __restrict__ Wc,
    const float* __restrict__ bc, int n, int mode)
{
    __shared__ float sWc[HID * WCPAD];
    __shared__ float sbc[OUT_DIM];
    if (mode == 1) {
        for (int i = threadIdx.x; i < HID * OUT_DIM; i += 256)
            sWc[(i / OUT_DIM) * WCPAD + (i % OUT_DIM)] = Wc[i];
        if (threadIdx.x < OUT_DIM) sbc[threadIdx.x] = bc[threadIdx.x];
        __syncthreads();
    }

    int wid = threadIdx.x >> 6;
    int node = (blockIdx.x << 2) + wid;
    if (node >= n) return;
    int lane = threadIdx.x & 63;
    int H = lane >> 5;
    int p = lane & 31;

    const half2v c02 = { (_Float16)0.2f, (_Float16)0.2f };

    half8 xrh = *(const half8*)(xr + (size_t)node * HIDHC + p * 8);
    half2v xr01 = __builtin_shufflevector(xrh, xrh, 0, 1);
    half2v xr23 = __builtin_shufflevector(xrh, xrh, 2, 3);
    half2v xr45 = __builtin_shufflevector(xrh, xrh, 4, 5);
    half2v xr67 = __builtin_shufflevector(xrh, xrh, 6, 7);

    float4 af0 = *(const float4*)(att + p * 8);
    float4 af1 = *(const float4*)(att + p * 8 + 4);
    half2v at01 = { (_Float16)af0.x, (_Float16)af0.y };
    half2v at23 = { (_Float16)af0.z, (_Float16)af0.w };
    half2v at45 = { (_Float16)af1.x, (_Float16)af1.y };
    half2v at67 = { (_Float16)af1.z, (_Float16)af1.w };

    float acc[8];
    #pragma unroll
    for (int k = 0; k < 8; ++k) acc[k] = 0.f;
    float d = 0.f;

    int j0 = __builtin_amdgcn_readfirstlane(offsets[node]);
    int j1 = __builtin_amdgcn_readfirstlane(offsets[node + 1]);

    int j = j0;
    for (; j + 2 <= j1; j += 2) {
        int s0 = __builtin_amdgcn_readfirstlane(csr_src[j]);
        int s1 = __builtin_amdgcn_readfirstlane(csr_src[j + 1]);
        int s = H ? s1 : s0;
        half8 h = *(const half8*)(xl + (size_t)s * HIDHC + p * 8);
        half2v h01 = __builtin_shufflevector(h, h, 0, 1);
        half2v h23 = __builtin_shufflevector(h, h, 2, 3);
        half2v h45 = __builtin_shufflevector(h, h, 4, 5);
        half2v h67 = __builtin_shufflevector(h, h, 6, 7);
        half2v s01 = h01 + xr01, s23 = h23 + xr23, s45 = h45 + xr45, s67 = h67 + xr67;
        half2v l01 = __builtin_elementwise_max(s01, s01 * c02);
        half2v l23 = __builtin_elementwise_max(s23, s23 * c02);
        half2v l45 = __builtin_elementwise_max(s45, s45 * c02);
        half2v l67 = __builtin_elementwise_max(s67, s67 * c02);
        float e = __builtin_amdgcn_fdot2(l01, at01, 0.f, false);
        e = __builtin_amdgcn_fdot2(l23, at23, e, false);
        e = __builtin_amdgcn_fdot2(l45, at45, e, false);
        e = __builtin_amdgcn_fdot2(l67, at67, e, false);
        e += __shfl_xor(e, 1);
        e += __shfl_xor(e, 2);
        e += __shfl_xor(e, 4);
        float pw = __expf(e);
        d += pw;
        #pragma unroll
        for (int k = 0; k < 8; ++k) acc[k] = fmaf(pw, (float)h[k], acc[k]);
    }
    if (j < j1) {
        int s0 = __builtin_amdgcn_readfirstlane(csr_src[j]);
        half8 h = *(const half8*)(xl + (size_t)s0 * HIDHC + p * 8);
        half2v h01 = __builtin_shufflevector(h, h, 0, 1);
        half2v h23 = __builtin_shufflevector(h, h, 2, 3);
        half2v h45 = __builtin_shufflevector(h, h, 4, 5);
        half2v h67 = __builtin_shufflevector(h, h, 6, 7);
        half2v s01 = h01 + xr01, s23 = h23 + xr23, s45 = h45 + xr45, s67 = h67 + xr67;
        half2v l01 = __builtin_elementwise_max(s01, s01 * c02);
        half2v l23 = __builtin_elementwise_max(s23, s23 * c02);
        half2v l45 = __builtin_elementwise_max(s45, s45 * c02);
        half2v l67 = __builtin_elementwise_max(s67, s67 * c02);
        float e = __builtin_amdgcn_fdot2(l01, at01, 0.f, false);
        e = __builtin_amdgcn_fdot2(l23, at23, e, false);
        e = __builtin_amdgcn_fdot2(l45, at45, e, false);
        e = __builtin_amdgcn_fdot2(l67, at67, e, false);
        e += __shfl_xor(e, 1);
        e += __shfl_xor(e, 2);
        e += __shfl_xor(e, 4);
        float pw = (H == 0) ? __expf(e) : 0.f;
        d += pw;
        #pragma unroll
        for (int k = 0; k < 8; ++k) acc[k] = fmaf(pw, (float)h[k], acc[k]);
    }

    d += __shfl_xor(d, 32);
    #pragma unroll
    for (int k = 0; k < 8; ++k) acc[k] += __shfl_xor(acc[k], 32);

    float inv = 1.f / (d + 1e-16f);
    float o[8];
    #pragma unroll
    for (int k = 0; k < 8; ++k) o[k] = acc[k] * inv;

    if (mode == 0) {
        if (H == 0) {
            float4 b0 = *(const float4*)(bias + p * 8);
            float4 b1 = *(const float4*)(bias + p * 8 + 4);
            float bb[8] = { b0.x, b0.y, b0.z, b0.w, b1.x, b1.y, b1.z, b1.w };
            half8 hh;
            #pragma unroll
            for (int k = 0; k < 8; ++k) hh[k] = (_Float16)fmaxf(o[k] + bb[k], 0.f);
            *(half8*)((_Float16*)out0 + (size_t)node * HIDHC + p * 8) = hh;
        }
    } else {
        // head-mean over 4 heads -> every lane holds channels (lane&7)*8+k
        #pragma unroll
        for (int k = 0; k < 8; ++k) {
            o[k] += __shfl_xor(o[k], 8);
            o[k] += __shfl_xor(o[k], 16);
        }
        int c = lane & 7;          // channel-block index
        int g = lane >> 3;         // replica group: outputs 5g..5g+4
        float4 b0 = *(const float4*)(bias + c * 8);
        float4 b1 = *(const float4*)(bias + c * 8 + 4);
        float bb[8] = { b0.x, b0.y, b0.z, b0.w, b1.x, b1.y, b1.z, b1.w };
        float h2v[8];
        #pragma unroll
        for (int k = 0; k < 8; ++k) h2v[k] = fmaxf(o[k] * 0.25f + bb[k], 0.f);
        float partial[5];
        #pragma unroll
        for (int m = 0; m < 5; ++m) {
            float s = 0.f;
            #pragma unroll
            for (int k = 0; k < 8; ++k)
                s = fmaf(h2v[k], sWc[(c * 8 + k) * WCPAD + 5 * g + m], s);
            partial[m] = s;
        }
        #pragma unroll
        for (int m = 0; m < 5; ++m) {
            partial[m] += __shfl_xor(partial[m], 1);
            partial[m] += __shfl_xor(partial[m], 2);
            partial[m] += __shfl_xor(partial[m], 4);
        }
        if (c < 5) {
            int oidx = 5 * g + c;
            ((float*)out0)[(size_t)node * OUT_DIM + oidx] = partial[c] + sbc[oidx];
        }
    }
}

// -------------------- launch --------------------

extern "C" void kernel_launch(void* const* d_in, const int* in_sizes, int n_in,
                              void* d_out, int out_size, void* d_ws, size_t ws_size,
                              hipStream_t stream) {
    const int N = in_sizes[0] / IN_DIM;   // 50000
    const int E = in_sizes[1];            // 800000

    const float* x    = (const float*)d_in[0];
    const int*   src  = (const int*)d_in[1];
    const int*   dst  = (const int*)d_in[2];
    const float* Wl1  = (const float*)d_in[3];
    const float* bl1  = (const float*)d_in[4];
    const float* Wr1  = (const float*)d_in[5];
    const float* br1  = (const float*)d_in[6];
    const float* att1 = (const float*)d_in[7];
    const float* bias1= (const float*)d_in[8];
    const float* Wl2  = (const float*)d_in[9];
    const float* bl2  = (const float*)d_in[10];
    const float* Wr2  = (const float*)d_in[11];
    const float* br2  = (const float*)d_in[12];
    const float* att2 = (const float*)d_in[13];
    const float* bias2= (const float*)d_in[14];
    const float* Wc   = (const float*)d_in[15];
    const float* bc   = (const float*)d_in[16];

    char* ws = (char*)d_ws;
    size_t off = 0;
    _Float16* xlh = (_Float16*)(ws + off); off += (size_t)N * HIDHC * 2;  // xl fp16
    _Float16* xrh = (_Float16*)(ws + off); off += (size_t)N * HIDHC * 2;  // xr fp16
    _Float16* Af  = (_Float16*)(ws + off); off += (size_t)N * HIDHC * 2;  // x / h1 fp16
    _Float16* Wt  = (_Float16*)(ws + off); off += (size_t)4 * 65536 * 2;
    int* deg     = (int*)(ws + off); off += (size_t)N * 4;
    int* offsets = (int*)(ws + off); off += (size_t)(N + 1) * 4;
    int* cursor  = (int*)(ws + off); off += (size_t)N * 4;
    int* csr     = (int*)(ws + off); off += (size_t)E * 4;
    int* bsum    = (int*)(ws + off); off += 256 * 4;
    int* bpre    = (int*)(ws + off); off += 256 * 4;

    const int NB = (N + 255) / 256;
    const int n4 = N * HIDHC / 4;
    const int nbCvt = (n4 + 255) / 256;
    const int nbW = 1024;
    const int nbE = (E + 255) / 256;
    const int Mb = (N + 127) / 128;
    const int KW = 65536;

    // 1) zero degree counters
    hipMemsetAsync(deg, 0, (size_t)N * 4, stream);
    // 2) fused prep: x->fp16, W->fp16^T, degree histogram
    prep_all<<<nbCvt + nbW + nbE, 256, 0, stream>>>(x, Af, n4,
        Wl1, Wr1, Wl2, Wr2, Wt, dst, deg, E, nbCvt, nbW);
    // 3-5) parallel scan -> offsets/cursor
    deg_block_reduce<<<NB, 256, 0, stream>>>(deg, bsum, N);
    scan_bsums<<<1, 256, 0, stream>>>(bsum, bpre, NB);
    deg_scan_apply<<<NB, 256, 0, stream>>>(deg, bpre, offsets, cursor, N);
    // 6) layer-1 GEMM + edge_scatter fused
    gemm_scatter<<<nbE + Mb * 4, 256, 0, stream>>>(Af,
        Wt + 0 * KW, bl1, xlh, Wt + 1 * KW, br1, xrh, N, Mb,
        src, dst, cursor, csr, E, nbE);
    // 7) layer-1 attention
    gat_node<<<(N + 3) / 4, 256, 0, stream>>>(xlh, xrh, att1, bias1, offsets, csr,
                                              (void*)Af, Wc, bc, N, 0);
    // 8) layer-2 GEMM
    gemm_scatter<<<Mb * 4, 256, 0, stream>>>(Af,
        Wt + 2 * KW, bl2, xlh, Wt + 3 * KW, br2, xrh, N, Mb,
        src, dst, cursor, csr, E, 0);
    // 9) layer-2 attention + fused head linear -> d_out
    gat_node<<<(N + 3) / 4, 256, 0, stream>>>(xlh, xrh, att2, bias2, offsets, csr,
                                              d_out, Wc, bc, N, 1);
}